// Round 11
// baseline (770.439 us; speedup 1.0000x reference)
//
#include <hip/hip_runtime.h>
#include <stdint.h>

#define HID    4096
#define SLEN   2048
#define BATCH  2
#define NHEADS 32
#define NKVH   8
#define HDIM   128
#define NTOK   (BATCH*SLEN)          // 4096
#define NQK    (NHEADS*HDIM)         // 4096
#define NKVD   (NKVH*HDIM)           // 1024
#define NQKV   (NQK + 2*NKVD)        // 6144
#define ASTR   (NQK + NKVD)          // 5120

typedef unsigned short u16;
typedef short short8 __attribute__((ext_vector_type(8)));
typedef float f32x4 __attribute__((ext_vector_type(4)));
typedef int int4v __attribute__((ext_vector_type(4)));
typedef u16 u16x4 __attribute__((ext_vector_type(4)));

static __device__ __forceinline__ u16 f2bf(float f) {
  unsigned u = __builtin_bit_cast(unsigned, f);
  u += 0x7FFFu + ((u >> 16) & 1u);
  return (u16)(u >> 16);
}
static __device__ __forceinline__ float bf2f(u16 h) {
  return __builtin_bit_cast(float, (unsigned)h << 16);
}
static __device__ __forceinline__ void gload_lds16(const void* g, void* l) {
  __builtin_amdgcn_global_load_lds((const __attribute__((address_space(1))) void*)g,
                                   (__attribute__((address_space(3))) void*)l, 16, 0, 0);
}

// ---------------- RMSNorm: f32 -> bf16 ----------------
__global__ __launch_bounds__(256) void k_rmsnorm(const float* __restrict__ x,
                                                 const float* __restrict__ w,
                                                 u16* __restrict__ h) {
  const int row = blockIdx.x;
  const float4* xr = (const float4*)(x + (size_t)row * HID);
  float4 vals[4];
  float ss = 0.f;
#pragma unroll
  for (int i = 0; i < 4; ++i) {
    float4 v = xr[threadIdx.x + i * 256];
    vals[i] = v;
    ss += v.x*v.x + v.y*v.y + v.z*v.z + v.w*v.w;
  }
#pragma unroll
  for (int off = 32; off; off >>= 1) ss += __shfl_xor(ss, off);
  __shared__ float red[4];
  if ((threadIdx.x & 63) == 0) red[threadIdx.x >> 6] = ss;
  __syncthreads();
  ss = red[0] + red[1] + red[2] + red[3];
  const float scale = rsqrtf(ss * (1.f / HID) + 1e-6f);
  u16* hr = h + (size_t)row * HID;
#pragma unroll
  for (int i = 0; i < 4; ++i) {
    int c = (threadIdx.x + i * 256) * 4;
    float4 v = vals[i];
    unsigned lo = (unsigned)f2bf(v.x * scale * w[c])   | ((unsigned)f2bf(v.y * scale * w[c+1]) << 16);
    unsigned hi = (unsigned)f2bf(v.z * scale * w[c+2]) | ((unsigned)f2bf(v.w * scale * w[c+3]) << 16);
    *(unsigned long long*)(hr + c) = ((unsigned long long)hi << 32) | lo;
  }
}

// ------- fused weight dequant: all four int4 matrices -> bf16 [10240][4096] -------
__global__ __launch_bounds__(256) void k_deq_all(
    const int* __restrict__ wq, const int* __restrict__ wk,
    const int* __restrict__ wv, const int* __restrict__ wo,
    const float* __restrict__ sq, const float* __restrict__ sk,
    const float* __restrict__ sv, const float* __restrict__ so,
    u16* __restrict__ out) {
  const int idx = blockIdx.x * 256 + threadIdx.x;  // 10240 rows * 512 chunks
  const int row = idx >> 9;
  const int k8 = (idx & 511) * 8;
  const int* W; const float* S; int r;
  if (row < 4096)      { W = wq; S = sq; r = row; }
  else if (row < 5120) { W = wk; S = sk; r = row - 4096; }
  else if (row < 6144) { W = wv; S = sv; r = row - 5120; }
  else                 { W = wo; S = so; r = row - 6144; }
  const float sc = S[r * 32 + (k8 >> 7)];
  int4v a = *(const int4v*)(W + (size_t)r * HID + k8);
  int4v b = *(const int4v*)(W + (size_t)r * HID + k8 + 4);
  u16 rr[8];
#pragma unroll
  for (int j = 0; j < 4; ++j) rr[j]     = f2bf((float)(a[j] - 8) * sc);
#pragma unroll
  for (int j = 0; j < 4; ++j) rr[j + 4] = f2bf((float)(b[j] - 8) * sc);
  *(short8*)(out + (size_t)row * HID + k8) = *(short8*)rr;
}

#define BM 128
#define BN 128
#define BK 64

// ------ pure bf16 QKV GEMM (2-phase, proven 277us) + XCD-chunked grid ------
// 1536 blocks 1D; XCD x owns wg [192x,192(x+1)) = 6 N-panels x 32 M-tiles,
// M innermost -> 1MB B-panel L2-resident across 32 consecutive blocks/XCD.
__global__ __launch_bounds__(256) void k_gemm_qkv_b(
    const u16* __restrict__ A, const u16* __restrict__ B,
    u16* __restrict__ C, u16* __restrict__ Vt) {
  __shared__ __align__(16) u16 lA[BM * BK];
  __shared__ __align__(16) u16 lB[BN * BK];
  const int tid = threadIdx.x;
  const int lane = tid & 63;
  const int wave = tid >> 6;
  const int wm = wave >> 1, wn = wave & 1;
  const int wg = (blockIdx.x & 7) * 192 + (blockIdx.x >> 3);  // bijective (1536%8==0)
  const int m0 = (wg & 31) * BM;
  const int n0 = (wg >> 5) * BN;

  const int rloc = wave * 8 + (lane >> 3);
  const int lb8 = (((lane & 7) ^ (lane >> 3)) << 3);

  f32x4 acc[4][4];
#pragma unroll
  for (int mi = 0; mi < 4; ++mi)
#pragma unroll
    for (int ni = 0; ni < 4; ++ni) acc[mi][ni] = (f32x4){0.f, 0.f, 0.f, 0.f};

  for (int k0 = 0; k0 < HID; k0 += BK) {
    __syncthreads();
#pragma unroll
    for (int p = 0; p < 4; ++p)
      gload_lds16(A + (size_t)(m0 + p * 32 + rloc) * HID + k0 + lb8,
                  lA + p * 2048 + wave * 512);
#pragma unroll
    for (int p = 0; p < 4; ++p)
      gload_lds16(B + (size_t)(n0 + p * 32 + rloc) * HID + k0 + lb8,
                  lB + p * 2048 + wave * 512);
    __syncthreads();
#pragma unroll
    for (int kc = 0; kc < 2; ++kc) {
      const int kOff = kc * 32 + ((lane >> 4) << 3);
      short8 af[4], bfr[4];
#pragma unroll
      for (int i = 0; i < 4; ++i) {
        const int m = wm * 64 + i * 16 + (lane & 15);
        af[i] = *(const short8*)(lA + ((m * 64 + kOff) ^ ((m & 7) << 3)));
        const int n = wn * 64 + i * 16 + (lane & 15);
        bfr[i] = *(const short8*)(lB + ((n * 64 + kOff) ^ ((n & 7) << 3)));
      }
#pragma unroll
      for (int mi = 0; mi < 4; ++mi)
#pragma unroll
        for (int ni = 0; ni < 4; ++ni)
          acc[mi][ni] = __builtin_amdgcn_mfma_f32_16x16x32_bf16(af[mi], bfr[ni], acc[mi][ni], 0, 0, 0);
    }
  }
  if (n0 < ASTR) {
#pragma unroll
    for (int mi = 0; mi < 4; ++mi) {
      const int row = m0 + wm * 64 + mi * 16 + ((lane >> 4) << 2);
#pragma unroll
      for (int ni = 0; ni < 4; ++ni) {
        const int col = n0 + wn * 64 + ni * 16 + (lane & 15);
#pragma unroll
        for (int r = 0; r < 4; ++r)
          C[(size_t)(row + r) * ASTR + col] = f2bf(acc[mi][ni][r]);
      }
    }
  } else {
#pragma unroll
    for (int mi = 0; mi < 4; ++mi) {
      const int row = m0 + wm * 64 + mi * 16 + ((lane >> 4) << 2);
      const int b_ = row >> 11, s_ = row & 2047;
#pragma unroll
      for (int ni = 0; ni < 4; ++ni) {
        const int colv = (n0 - ASTR) + wn * 64 + ni * 16 + (lane & 15);
        u16x4 pk;
#pragma unroll
        for (int r = 0; r < 4; ++r) pk[r] = f2bf(acc[mi][ni][r]);
        *(u16x4*)(Vt + ((size_t)(b_ * NKVH + (colv >> 7)) * HDIM + (colv & 127)) * SLEN + s_) = pk;
      }
    }
  }
}

// ============ 256x256 8-phase GEMM body (r4-proven, for o-proj) ============
#define KD 4096
#define NT 64

#define STAGE_A_(nb, kt, mh)                                                   \
  { _Pragma("unroll") for (int r_ = 0; r_ < 2; ++r_) {                         \
      const int base_ = (mh)*64 + r_*128 + wave*8;                             \
      const int lr_ = base_ + (lane>>3);                                       \
      gload_lds16(Ag + (size_t)(m0 + lr_)*KD + (kt)*64 + (((lane&7) ^ (lr_&7))<<3), \
                  lA[nb] + base_*64); } }

#define STAGE_B_(nb, kt, nh)                                                   \
  { _Pragma("unroll") for (int r_ = 0; r_ < 2; ++r_) {                         \
      const int w8_ = r_*64 + wave*8;                                          \
      const int base_ = ((w8_>>5)<<6) + (nh)*32 + (w8_&31);                    \
      const int nr_ = base_ + (lane>>3);                                       \
      gload_lds16(Bg + (size_t)(n0 + nr_)*KD + (kt)*64 + (((lane&7) ^ (nr_&7))<<3), \
                  lB[nb] + base_*64); } }

#define DS_PHASE(buf, mh, nh)                                                  \
  { const int kb_ = lane >> 4;                                                 \
    _Pragma("unroll") for (int ks = 0; ks < 2; ++ks) {                         \
      _Pragma("unroll") for (int i = 0; i < 4; ++i) {                          \
        const int lr_ = wm*128 + (mh)*64 + i*16 + (lane & 15);                 \
        af[i][ks] = *(const short8*)(lA[buf] + lr_*64 + (((ks*4+kb_) ^ (lr_&7))<<3)); } \
      _Pragma("unroll") for (int j = 0; j < 2; ++j) {                          \
        const int nr_ = wn*64 + (nh)*32 + j*16 + (lane & 15);                  \
        bf[j][ks] = *(const short8*)(lB[buf] + nr_*64 + (((ks*4+kb_) ^ (nr_&7))<<3)); } } }

#define MFMA_PHASE(mh, nh)                                                     \
  __builtin_amdgcn_s_setprio(1);                                               \
  _Pragma("unroll") for (int ks = 0; ks < 2; ++ks)                             \
    _Pragma("unroll") for (int i = 0; i < 4; ++i)                              \
      _Pragma("unroll") for (int j = 0; j < 2; ++j)                            \
        acc[(mh)*4+i][(nh)*2+j] = __builtin_amdgcn_mfma_f32_16x16x32_bf16(     \
            af[i][ks], bf[j][ks], acc[(mh)*4+i][(nh)*2+j], 0, 0, 0);           \
  __builtin_amdgcn_s_setprio(0);

#define BAR()  __builtin_amdgcn_s_barrier(); asm volatile("" ::: "memory")
#define VMW(n) asm volatile("s_waitcnt vmcnt(" #n ")" ::: "memory")

#define GEMM8P_BODY                                                            \
  __shared__ __align__(16) u16 lA[2][256*64];                                  \
  __shared__ __align__(16) u16 lB[2][256*64];                                  \
  const int tid = threadIdx.x, lane = tid & 63, wave = tid >> 6;               \
  const int wm = wave >> 2, wn = wave & 3;                                     \
  f32x4 acc[8][4];                                                             \
  _Pragma("unroll") for (int mi = 0; mi < 8; ++mi)                             \
    _Pragma("unroll") for (int ni = 0; ni < 4; ++ni)                           \
      acc[mi][ni] = (f32x4){0.f, 0.f, 0.f, 0.f};                               \
  short8 af[4][2], bf[2][2];                                                   \
  STAGE_A_(0, 0, 0); STAGE_B_(0, 0, 0); STAGE_A_(0, 0, 1); STAGE_B_(0, 0, 1);  \
  VMW(4); BAR();                                                               \
  for (int t = 0; t < NT - 1; ++t) {                                           \
    const int cur = t & 1, nxt = cur ^ 1;                                      \
    DS_PHASE(cur, 0, 0);                                                       \
    STAGE_A_(nxt, t + 1, 0);                                                   \
    BAR();                                                                     \
    MFMA_PHASE(0, 0);                                                          \
    VMW(2); BAR();                                                             \
    DS_PHASE(cur, 0, 1);                                                       \
    STAGE_B_(nxt, t + 1, 0);                                                   \
    BAR();                                                                     \
    MFMA_PHASE(0, 1);                                                          \
    BAR();                                                                     \
    DS_PHASE(cur, 1, 0);                                                       \
    STAGE_A_(nxt, t + 1, 1);                                                   \
    BAR();                                                                     \
    MFMA_PHASE(1, 0);                                                          \
    BAR();                                                                     \
    DS_PHASE(cur, 1, 1);                                                       \
    STAGE_B_(nxt, t + 1, 1);                                                   \
    BAR();                                                                     \
    MFMA_PHASE(1, 1);                                                          \
    VMW(4); BAR();                                                             \
  }                                                                            \
  {                                                                            \
    const int cur = (NT - 1) & 1;                                              \
    DS_PHASE(cur, 0, 0);                                                       \
    BAR();                                                                     \
    MFMA_PHASE(0, 0);                                                          \
    VMW(0); BAR();                                                             \
    DS_PHASE(cur, 0, 1);                                                       \
    BAR();                                                                     \
    MFMA_PHASE(0, 1);                                                          \
    BAR();                                                                     \
    DS_PHASE(cur, 1, 0);                                                       \
    BAR();                                                                     \
    MFMA_PHASE(1, 0);                                                          \
    BAR();                                                                     \
    DS_PHASE(cur, 1, 1);                                                       \
    BAR();                                                                     \
    MFMA_PHASE(1, 1);                                                          \
  }

__global__ __launch_bounds__(512, 2) void k_gemm_o_8p(
    const u16* __restrict__ Ag, const u16* __restrict__ Bg,
    const float* __restrict__ resid, float* __restrict__ out) {
  // 256 blocks, XCD-chunked bijective remap
  const int wg = (blockIdx.x & 7) * 32 + (blockIdx.x >> 3);
  const int m0 = (wg & 15) * 256;
  const int n0 = (wg >> 4) * 256;
  GEMM8P_BODY
#pragma unroll
  for (int mi = 0; mi < 8; ++mi) {
    const int row = m0 + wm * 128 + mi * 16 + ((lane >> 4) << 2);
#pragma unroll
    for (int ni = 0; ni < 4; ++ni) {
      const int col = n0 + wn * 64 + ni * 16 + (lane & 15);
#pragma unroll
      for (int r = 0; r < 4; ++r) {
        const size_t idx = (size_t)(row + r) * HID + col;
        out[idx] = acc[mi][ni][r] + resid[idx];
      }
    }
  }
}

// ---------------- fused-dequant GEMMs (fallback when ws is small) ----------------
__global__ __launch_bounds__(256) void k_gemm_qkv(
    const u16* __restrict__ A,
    const int* __restrict__ Wq, const int* __restrict__ Wk, const int* __restrict__ Wv,
    const float* __restrict__ Sq, const float* __restrict__ Sk, const float* __restrict__ Sv,
    u16* __restrict__ C, u16* __restrict__ Vt) {
  __shared__ __align__(16) u16 lA[BM * BK];
  __shared__ __align__(16) u16 lB[BN * BK];
  const int tid = threadIdx.x;
  const int lane = tid & 63;
  const int wave = tid >> 6;
  const int wm = wave >> 1, wn = wave & 1;
  const int m0 = blockIdx.x * BM;
  const int n0 = blockIdx.y * BN;

  const int* W; const float* Ws; int nb;
  if (n0 < NQK)       { W = Wq; Ws = Sq; nb = n0; }
  else if (n0 < ASTR) { W = Wk; Ws = Sk; nb = n0 - NQK; }
  else                { W = Wv; Ws = Sv; nb = n0 - ASTR; }

  const int mloc = wave * 8 + (lane >> 3);
  const int lb8 = (((lane & 7) ^ (lane >> 3)) << 3);

  f32x4 acc[4][4];
#pragma unroll
  for (int mi = 0; mi < 4; ++mi)
#pragma unroll
    for (int ni = 0; ni < 4; ++ni) acc[mi][ni] = (f32x4){0.f, 0.f, 0.f, 0.f};

  for (int k0 = 0; k0 < HID; k0 += BK) {
    __syncthreads();
#pragma unroll
    for (int p = 0; p < 4; ++p)
      gload_lds16(A + (size_t)(m0 + p * 32 + mloc) * HID + k0 + lb8,
                  lA + p * 2048 + wave * 512);
    const int grp = k0 >> 7;
#pragma unroll
    for (int p = 0; p < 8; ++p) {
      const int n = p * 16 + (tid >> 4);
      const int kk = (tid & 15) * 4;
      int4v wv4 = *(const int4v*)(W + (size_t)(nb + n) * HID + k0 + kk);
      const float sc = Ws[(nb + n) * 32 + grp];
      unsigned lo = (unsigned)f2bf((float)(wv4[0] - 8) * sc) |
                    ((unsigned)f2bf((float)(wv4[1] - 8) * sc) << 16);
      unsigned hi = (unsigned)f2bf((float)(wv4[2] - 8) * sc) |
                    ((unsigned)f2bf((float)(wv4[3] - 8) * sc) << 16);
      const int di = (n * 64 + kk) ^ ((n & 7) << 3);
      unsigned* dst = (unsigned*)(lB + di);
      dst[0] = lo; dst[1] = hi;
    }
    __syncthreads();
#pragma unroll
    for (int kc = 0; kc < 2; ++kc) {
      const int kOff = kc * 32 + ((lane >> 4) << 3);
      short8 af[4], bfr[4];
#pragma unroll
      for (int i = 0; i < 4; ++i) {
        const int m = wm * 64 + i * 16 + (lane & 15);
        af[i] = *(const short8*)(lA + ((m * 64 + kOff) ^ ((m & 7) << 3)));
        const int n = wn * 64 + i * 16 + (lane & 15);
        bfr[i] = *(const short8*)(lB + ((n * 64 + kOff) ^ ((n & 7) << 3)));
      }
#pragma unroll
      for (int mi = 0; mi < 4; ++mi)
#pragma unroll
        for (int ni = 0; ni < 4; ++ni)
          acc[mi][ni] = __builtin_amdgcn_mfma_f32_16x16x32_bf16(af[mi], bfr[ni], acc[mi][ni], 0, 0, 0);
    }
  }
  if (n0 < ASTR) {
#pragma unroll
    for (int mi = 0; mi < 4; ++mi) {
      const int row = m0 + wm * 64 + mi * 16 + ((lane >> 4) << 2);
#pragma unroll
      for (int ni = 0; ni < 4; ++ni) {
        const int col = n0 + wn * 64 + ni * 16 + (lane & 15);
#pragma unroll
        for (int r = 0; r < 4; ++r)
          C[(size_t)(row + r) * ASTR + col] = f2bf(acc[mi][ni][r]);
      }
    }
  } else {
#pragma unroll
    for (int mi = 0; mi < 4; ++mi) {
      const int row = m0 + wm * 64 + mi * 16 + ((lane >> 4) << 2);
      const int b_ = row >> 11, s_ = row & 2047;
#pragma unroll
      for (int ni = 0; ni < 4; ++ni) {
        const int colv = (n0 - ASTR) + wn * 64 + ni * 16 + (lane & 15);
        u16x4 pk;
#pragma unroll
        for (int r = 0; r < 4; ++r) pk[r] = f2bf(acc[mi][ni][r]);
        *(u16x4*)(Vt + ((size_t)(b_ * NKVH + (colv >> 7)) * HDIM + (colv & 127)) * SLEN + s_) = pk;
      }
    }
  }
}

__global__ __launch_bounds__(256) void k_gemm_o(
    const u16* __restrict__ A, const int* __restrict__ W, const float* __restrict__ Ws,
    const float* __restrict__ resid, float* __restrict__ out) {
  __shared__ __align__(16) u16 lA[BM * BK];
  __shared__ __align__(16) u16 lB[BN * BK];
  const int tid = threadIdx.x;
  const int lane = tid & 63;
  const int wave = tid >> 6;
  const int wm = wave >> 1, wn = wave & 1;
  const int m0 = blockIdx.x * BM;
  const int n0 = blockIdx.y * BN;

  const int mloc = wave * 8 + (lane >> 3);
  const int lb8 = (((lane & 7) ^ (lane >> 3)) << 3);

  f32x4 acc[4][4];
#pragma unroll
  for (int mi = 0; mi < 4; ++mi)
#pragma unroll
    for (int ni = 0; ni < 4; ++ni) acc[mi][ni] = (f32x4){0.f, 0.f, 0.f, 0.f};

  for (int k0 = 0; k0 < NQK; k0 += BK) {
    __syncthreads();
#pragma unroll
    for (int p = 0; p < 4; ++p)
      gload_lds16(A + (size_t)(m0 + p * 32 + mloc) * NQK + k0 + lb8,
                  lA + p * 2048 + wave * 512);
    const int grp = k0 >> 7;
#pragma unroll
    for (int p = 0; p < 8; ++p) {
      const int n = p * 16 + (tid >> 4);
      const int kk = (tid & 15) * 4;
      int4v wv4 = *(const int4v*)(W + (size_t)(n0 + n) * NQK + k0 + kk);
      const float sc = Ws[(n0 + n) * 32 + grp];
      unsigned lo = (unsigned)f2bf((float)(wv4[0] - 8) * sc) |
                    ((unsigned)f2bf((float)(wv4[1] - 8) * sc) << 16);
      unsigned hi = (unsigned)f2bf((float)(wv4[2] - 8) * sc) |
                    ((unsigned)f2bf((float)(wv4[3] - 8) * sc) << 16);
      const int di = (n * 64 + kk) ^ ((n & 7) << 3);
      unsigned* dst = (unsigned*)(lB + di);
      dst[0] = lo; dst[1] = hi;
    }
    __syncthreads();
#pragma unroll
    for (int kc = 0; kc < 2; ++kc) {
      const int kOff = kc * 32 + ((lane >> 4) << 3);
      short8 af[4], bfr[4];
#pragma unroll
      for (int i = 0; i < 4; ++i) {
        const int m = wm * 64 + i * 16 + (lane & 15);
        af[i] = *(const short8*)(lA + ((m * 64 + kOff) ^ ((m & 7) << 3)));
        const int n = wn * 64 + i * 16 + (lane & 15);
        bfr[i] = *(const short8*)(lB + ((n * 64 + kOff) ^ ((n & 7) << 3)));
      }
#pragma unroll
      for (int mi = 0; mi < 4; ++mi)
#pragma unroll
        for (int ni = 0; ni < 4; ++ni)
          acc[mi][ni] = __builtin_amdgcn_mfma_f32_16x16x32_bf16(af[mi], bfr[ni], acc[mi][ni], 0, 0, 0);
      }
  }
#pragma unroll
  for (int mi = 0; mi < 4; ++mi) {
    const int row = m0 + wm * 64 + mi * 16 + ((lane >> 4) << 2);
#pragma unroll
    for (int ni = 0; ni < 4; ++ni) {
      const int col = n0 + wn * 64 + ni * 16 + (lane & 15);
#pragma unroll
      for (int r = 0; r < 4; ++r) {
        const size_t idx = (size_t)(row + r) * HID + col;
        out[idx] = acc[mi][ni][r] + resid[idx];
      }
    }
  }
}

// ------ RoPE in-place on q,k — vectorized short8 (8 d-pairs per thread) ------
__global__ __launch_bounds__(256) void k_rope(u16* __restrict__ qk,
                                              const float* __restrict__ cosb,
                                              const float* __restrict__ sinb) {
  const int idx = blockIdx.x * 256 + threadIdx.x;   // NTOK*40*8 total
  const int d8 = (idx & 7) * 8;                      // 0..56
  const int hh = (idx >> 3) % 40;
  const int t = idx / 320;
  const int col = (hh < 32) ? hh * HDIM : NQK + (hh - 32) * HDIM;
  u16* p = qk + (size_t)t * ASTR + col;
  const float* cb = cosb + (size_t)t * HDIM + d8;
  const float* sb = sinb + (size_t)t * HDIM + d8;
  float4 c0 = *(const float4*)cb, c1 = *(const float4*)(cb + 4);
  float4 s0 = *(const float4*)sb, s1 = *(const float4*)(sb + 4);
  const float cv[8] = {c0.x, c0.y, c0.z, c0.w, c1.x, c1.y, c1.z, c1.w};
  const float sv[8] = {s0.x, s0.y, s0.z, s0.w, s1.x, s1.y, s1.z, s1.w};
  short8 x1v = *(const short8*)(p + d8);
  short8 x2v = *(const short8*)(p + d8 + 64);
  u16 o1[8], o2[8];
#pragma unroll
  for (int j = 0; j < 8; ++j) {
    const float x1 = bf2f((u16)x1v[j]), x2 = bf2f((u16)x2v[j]);
    o1[j] = f2bf(x1 * cv[j] - x2 * sv[j]);
    o2[j] = f2bf(x2 * cv[j] + x1 * sv[j]);
  }
  *(short8*)(p + d8)      = *(short8*)o1;
  *(short8*)(p + d8 + 64) = *(short8*)o2;
}

// ---------------- flash attention (GQA, causal) — r9-proven (banked) ----------------
// 1024 blocks; block = 4 waves x 32 q-rows of one head; K+V staged via gload_lds;
// Pl stride-72 per-wave; s_setprio around MFMA clusters.
__global__ __launch_bounds__(256) void k_attn(const u16* __restrict__ qk,
                                              const u16* __restrict__ vt,
                                              u16* __restrict__ o) {
  const int slot = blockIdx.x;
  const int w = (slot & 7) * 128 + (slot >> 3);
  const int qi = 15 - (w & 15);
  const int h = (w >> 4) & 31;
  const int b = w >> 9;
  const int kvh = h >> 2;
  const int q0 = qi * 128;
  const int lane = threadIdx.x & 63, wave = threadIdx.x >> 6;
  const int m = lane & 15, kg = lane >> 4;

  const u16* Qb = qk + (size_t)b * SLEN * ASTR + h * HDIM;
  const u16* Kb = qk + (size_t)b * SLEN * ASTR + NQK + kvh * HDIM;
  const u16* Vb = vt + (size_t)(b * NKVH + kvh) * HDIM * SLEN;

  __shared__ __align__(16) u16 Kt[64 * 128];
  __shared__ __align__(16) u16 Vts[128 * 64];
  __shared__ __align__(16) u16 Pl[4][32 * 72];

  const int qr = q0 + wave * 32;
  short8 qf[2][4];
#pragma unroll
  for (int mi = 0; mi < 2; ++mi)
#pragma unroll
    for (int kc = 0; kc < 4; ++kc)
      qf[mi][kc] = *(const short8*)(Qb + (size_t)(qr + mi * 16 + m) * ASTR + kc * 32 + kg * 8);

  f32x4 oacc[2][8];
#pragma unroll
  for (int mi = 0; mi < 2; ++mi)
#pragma unroll
    for (int n = 0; n < 8; ++n) oacc[mi][n] = (f32x4){0.f, 0.f, 0.f, 0.f};
  float rm[2][4], rl[2][4];
#pragma unroll
  for (int mi = 0; mi < 2; ++mi)
#pragma unroll
    for (int r = 0; r < 4; ++r) { rm[mi][r] = -3.0e38f; rl[mi][r] = 0.f; }

  const float sscale = 0.08838834764831845f;
  const int nt = q0 / 64 + 2;
  for (int t = 0; t < nt; ++t) {
    const int kv0 = t * 64;
    __syncthreads();
#pragma unroll
    for (int p = 0; p < 4; ++p) {
      const int row = p * 16 + wave * 4 + (lane >> 4);
      const int c8s = (lane & 15) ^ (row & 7);
      gload_lds16(Kb + (size_t)(kv0 + row) * ASTR + c8s * 8, Kt + p * 2048 + wave * 512);
    }
#pragma unroll
    for (int p = 0; p < 4; ++p) {
      const int d = p * 32 + wave * 8 + (lane >> 3);
      const int c8s = (lane & 7) ^ (d & 7);
      gload_lds16(Vb + (size_t)d * SLEN + kv0 + c8s * 8, Vts + p * 2048 + wave * 512);
    }
    __syncthreads();

    f32x4 sf[2][4];
#pragma unroll
    for (int mi = 0; mi < 2; ++mi)
#pragma unroll
      for (int ni = 0; ni < 4; ++ni) sf[mi][ni] = (f32x4){0.f, 0.f, 0.f, 0.f};
    __builtin_amdgcn_s_setprio(1);
#pragma unroll
    for (int ni = 0; ni < 4; ++ni)
#pragma unroll
      for (int kc = 0; kc < 4; ++kc) {
        const int krow = ni * 16 + m;
        short8 kf = *(const short8*)(Kt + krow * 128 + (((kc * 4 + kg) ^ (krow & 7)) << 3));
#pragma unroll
        for (int mi = 0; mi < 2; ++mi)
          sf[mi][ni] = __builtin_amdgcn_mfma_f32_16x16x32_bf16(qf[mi][kc], kf, sf[mi][ni], 0, 0, 0);
      }
    __builtin_amdgcn_s_setprio(0);

#pragma unroll
    for (int mi = 0; mi < 2; ++mi) {
      const bool dg = (kv0 + 63 > qr + mi * 16);
      float tmax[4] = {-3.0e38f, -3.0e38f, -3.0e38f, -3.0e38f};
#pragma unroll
      for (int ni = 0; ni < 4; ++ni)
#pragma unroll
        for (int r = 0; r < 4; ++r) {
          float s = sf[mi][ni][r] * sscale;
          if (dg) {
            const int rowg = qr + mi * 16 + kg * 4 + r;
            const int colg = kv0 + ni * 16 + m;
            if (colg > rowg) s = -1e30f;
          }
          sf[mi][ni][r] = s;
          tmax[r] = fmaxf(tmax[r], s);
        }
#pragma unroll
      for (int r = 0; r < 4; ++r)
#pragma unroll
        for (int off = 1; off < 16; off <<= 1)
          tmax[r] = fmaxf(tmax[r], __shfl_xor(tmax[r], off));
      float scl[4], psum[4];
#pragma unroll
      for (int r = 0; r < 4; ++r) {
        const float mn = fmaxf(rm[mi][r], tmax[r]);
        scl[r] = __expf(rm[mi][r] - mn);
        rm[mi][r] = mn;
        psum[r] = 0.f;
      }
#pragma unroll
      for (int ni = 0; ni < 4; ++ni)
#pragma unroll
        for (int r = 0; r < 4; ++r) {
          const float p = __expf(sf[mi][ni][r] - rm[mi][r]);
          psum[r] += p;
          Pl[wave][(mi * 16 + kg * 4 + r) * 72 + ni * 16 + m] = f2bf(p);
        }
#pragma unroll
      for (int r = 0; r < 4; ++r) {
#pragma unroll
        for (int off = 1; off < 16; off <<= 1)
          psum[r] += __shfl_xor(psum[r], off);
        rl[mi][r] = rl[mi][r] * scl[r] + psum[r];
      }
#pragma unroll
      for (int n = 0; n < 8; ++n)
#pragma unroll
        for (int r = 0; r < 4; ++r) oacc[mi][n][r] *= scl[r];
    }

    __builtin_amdgcn_s_setprio(1);
#pragma unroll
    for (int kc = 0; kc < 2; ++kc) {
      short8 pf[2];
#pragma unroll
      for (int mi = 0; mi < 2; ++mi)
        pf[mi] = *(const short8*)(&Pl[wave][(mi * 16 + m) * 72 + kc * 32 + kg * 8]);
#pragma unroll
      for (int n = 0; n < 8; ++n) {
        const int vrow = n * 16 + m;
        short8 vf = *(const short8*)(Vts + vrow * 64 + (((kc * 4 + kg) ^ (vrow & 7)) << 3));
#pragma unroll
        for (int mi = 0; mi < 2; ++mi)
          oacc[mi][n] = __builtin_amdgcn_mfma_f32_16x16x32_bf16(pf[mi], vf, oacc[mi][n], 0, 0, 0);
      }
    }
    __builtin_amdgcn_s_setprio(0);
  }

#pragma unroll
  for (int mi = 0; mi < 2; ++mi) {
    float inv[4];
#pragma unroll
    for (int r = 0; r < 4; ++r) inv[r] = 1.0f / rl[mi][r];
#pragma unroll
    for (int n = 0; n < 8; ++n)
#pragma unroll
      for (int r = 0; r < 4; ++r) {
        const int row = qr + mi * 16 + kg * 4 + r;
        o[((size_t)b * SLEN + row) * NQK + h * HDIM + n * 16 + m] = f2bf(oacc[mi][n][r] * inv[r]);
      }
  }
}

extern "C" void kernel_launch(void* const* d_in, const int* in_sizes, int n_in,
                              void* d_out, int out_size, void* d_ws, size_t ws_size,
                              hipStream_t stream) {
  (void)in_sizes; (void)n_in; (void)out_size;
  const float* x    = (const float*)d_in[0];
  const float* lnw  = (const float*)d_in[1];
  const float* cosb = (const float*)d_in[2];
  const float* sinb = (const float*)d_in[3];
  const float* sq   = (const float*)d_in[4];
  const float* sk   = (const float*)d_in[5];
  const float* sv   = (const float*)d_in[6];
  const float* so   = (const float*)d_in[7];
  const int* wq     = (const int*)d_in[8];
  const int* wk     = (const int*)d_in[9];
  const int* wv     = (const int*)d_in[10];
  const int* wo     = (const int*)d_in[11];

  u16* h   = (u16*)d_ws;                       // [NTOK][HID]; reused as attn output
  u16* qkb = h + (size_t)NTOK * HID;           // [NTOK][ASTR] (q,k)
  u16* vtb = qkb + (size_t)NTOK * ASTR;        // [B][NKVH][HDIM][SLEN]
  u16* wqkvb = vtb + (size_t)BATCH * NKVH * HDIM * SLEN;  // [NQKV][HID] bf16
  u16* wob   = wqkvb + (size_t)NQKV * HID;                // [HID][NQK] bf16
  float* out = (float*)d_out;

  const size_t need = ((size_t)NTOK * HID + (size_t)NTOK * ASTR +
                       (size_t)BATCH * NKVH * HDIM * SLEN +
                       (size_t)NQKV * HID + (size_t)HID * NQK) * sizeof(u16);
  const bool predeq = (ws_size >= need);

  k_rmsnorm<<<NTOK, 256, 0, stream>>>(x, lnw, h);

  if (predeq) {
    k_deq_all<<<(10240 * 512) / 256, 256, 0, stream>>>(wq, wk, wv, wo, sq, sk, sv, so, wqkvb);
    k_gemm_qkv_b<<<1536, 256, 0, stream>>>(h, wqkvb, qkb, vtb);
  } else {
    dim3 g1(NTOK / BM, NQKV / BN);
    k_gemm_qkv<<<g1, 256, 0, stream>>>(h, wq, wk, wv, sq, sk, sv, qkb, vtb);
  }

  k_rope<<<(NTOK * 40 * 8) / 256, 256, 0, stream>>>(qkb, cosb, sinb);

  k_attn<<<1024, 256, 0, stream>>>(qkb, vtb, h);

  if (predeq) {
    k_gemm_o_8p<<<256, 512, 0, stream>>>(h, wob, x, out);
  } else {
    dim3 g3(NTOK / BM, HID / BN);
    k_gemm_o<<<g3, 256, 0, stream>>>(h, wo, so, x, out);
  }
}

// Round 12
// 701.989 us; speedup vs baseline: 1.0975x; 1.0975x over previous
//
#include <hip/hip_runtime.h>
#include <stdint.h>

#define HID    4096
#define SLEN   2048
#define BATCH  2
#define NHEADS 32
#define NKVH   8
#define HDIM   128
#define NTOK   (BATCH*SLEN)          // 4096
#define NQK    (NHEADS*HDIM)         // 4096
#define NKVD   (NKVH*HDIM)           // 1024
#define NQKV   (NQK + 2*NKVD)        // 6144
#define ASTR   (NQK + NKVD)          // 5120

typedef unsigned short u16;
typedef short short8 __attribute__((ext_vector_type(8)));
typedef float f32x4 __attribute__((ext_vector_type(4)));
typedef int int4v __attribute__((ext_vector_type(4)));
typedef u16 u16x4 __attribute__((ext_vector_type(4)));

static __device__ __forceinline__ u16 f2bf(float f) {
  unsigned u = __builtin_bit_cast(unsigned, f);
  u += 0x7FFFu + ((u >> 16) & 1u);
  return (u16)(u >> 16);
}
static __device__ __forceinline__ float bf2f(u16 h) {
  return __builtin_bit_cast(float, (unsigned)h << 16);
}
static __device__ __forceinline__ void gload_lds16(const void* g, void* l) {
  __builtin_amdgcn_global_load_lds((const __attribute__((address_space(1))) void*)g,
                                   (__attribute__((address_space(3))) void*)l, 16, 0, 0);
}

// ---------------- RMSNorm: f32 -> bf16 ----------------
__global__ __launch_bounds__(256) void k_rmsnorm(const float* __restrict__ x,
                                                 const float* __restrict__ w,
                                                 u16* __restrict__ h) {
  const int row = blockIdx.x;
  const float4* xr = (const float4*)(x + (size_t)row * HID);
  float4 vals[4];
  float ss = 0.f;
#pragma unroll
  for (int i = 0; i < 4; ++i) {
    float4 v = xr[threadIdx.x + i * 256];
    vals[i] = v;
    ss += v.x*v.x + v.y*v.y + v.z*v.z + v.w*v.w;
  }
#pragma unroll
  for (int off = 32; off; off >>= 1) ss += __shfl_xor(ss, off);
  __shared__ float red[4];
  if ((threadIdx.x & 63) == 0) red[threadIdx.x >> 6] = ss;
  __syncthreads();
  ss = red[0] + red[1] + red[2] + red[3];
  const float scale = rsqrtf(ss * (1.f / HID) + 1e-6f);
  u16* hr = h + (size_t)row * HID;
#pragma unroll
  for (int i = 0; i < 4; ++i) {
    int c = (threadIdx.x + i * 256) * 4;
    float4 v = vals[i];
    unsigned lo = (unsigned)f2bf(v.x * scale * w[c])   | ((unsigned)f2bf(v.y * scale * w[c+1]) << 16);
    unsigned hi = (unsigned)f2bf(v.z * scale * w[c+2]) | ((unsigned)f2bf(v.w * scale * w[c+3]) << 16);
    *(unsigned long long*)(hr + c) = ((unsigned long long)hi << 32) | lo;
  }
}

// ------- fused weight dequant: all four int4 matrices -> bf16 [10240][4096] -------
__global__ __launch_bounds__(256) void k_deq_all(
    const int* __restrict__ wq, const int* __restrict__ wk,
    const int* __restrict__ wv, const int* __restrict__ wo,
    const float* __restrict__ sq, const float* __restrict__ sk,
    const float* __restrict__ sv, const float* __restrict__ so,
    u16* __restrict__ out) {
  const int idx = blockIdx.x * 256 + threadIdx.x;  // 10240 rows * 512 chunks
  const int row = idx >> 9;
  const int k8 = (idx & 511) * 8;
  const int* W; const float* S; int r;
  if (row < 4096)      { W = wq; S = sq; r = row; }
  else if (row < 5120) { W = wk; S = sk; r = row - 4096; }
  else if (row < 6144) { W = wv; S = sv; r = row - 5120; }
  else                 { W = wo; S = so; r = row - 6144; }
  const float sc = S[r * 32 + (k8 >> 7)];
  int4v a = *(const int4v*)(W + (size_t)r * HID + k8);
  int4v b = *(const int4v*)(W + (size_t)r * HID + k8 + 4);
  u16 rr[8];
#pragma unroll
  for (int j = 0; j < 4; ++j) rr[j]     = f2bf((float)(a[j] - 8) * sc);
#pragma unroll
  for (int j = 0; j < 4; ++j) rr[j + 4] = f2bf((float)(b[j] - 8) * sc);
  *(short8*)(out + (size_t)row * HID + k8) = *(short8*)rr;
}

#define BM 128
#define BN 128
#define BK 64

// ---------------- pure bf16 QKV GEMM (2-phase, r9-exact, proven 277us) ----------------
__global__ __launch_bounds__(256) void k_gemm_qkv_b(
    const u16* __restrict__ A, const u16* __restrict__ B,
    u16* __restrict__ C, u16* __restrict__ Vt) {
  __shared__ __align__(16) u16 lA[BM * BK];
  __shared__ __align__(16) u16 lB[BN * BK];
  const int tid = threadIdx.x;
  const int lane = tid & 63;
  const int wave = tid >> 6;
  const int wm = wave >> 1, wn = wave & 1;
  const int m0 = blockIdx.x * BM;
  const int n0 = blockIdx.y * BN;

  const int rloc = wave * 8 + (lane >> 3);
  const int lb8 = (((lane & 7) ^ (lane >> 3)) << 3);

  f32x4 acc[4][4];
#pragma unroll
  for (int mi = 0; mi < 4; ++mi)
#pragma unroll
    for (int ni = 0; ni < 4; ++ni) acc[mi][ni] = (f32x4){0.f, 0.f, 0.f, 0.f};

  for (int k0 = 0; k0 < HID; k0 += BK) {
    __syncthreads();
#pragma unroll
    for (int p = 0; p < 4; ++p)
      gload_lds16(A + (size_t)(m0 + p * 32 + rloc) * HID + k0 + lb8,
                  lA + p * 2048 + wave * 512);
#pragma unroll
    for (int p = 0; p < 4; ++p)
      gload_lds16(B + (size_t)(n0 + p * 32 + rloc) * HID + k0 + lb8,
                  lB + p * 2048 + wave * 512);
    __syncthreads();
#pragma unroll
    for (int kc = 0; kc < 2; ++kc) {
      const int kOff = kc * 32 + ((lane >> 4) << 3);
      short8 af[4], bfr[4];
#pragma unroll
      for (int i = 0; i < 4; ++i) {
        const int m = wm * 64 + i * 16 + (lane & 15);
        af[i] = *(const short8*)(lA + ((m * 64 + kOff) ^ ((m & 7) << 3)));
        const int n = wn * 64 + i * 16 + (lane & 15);
        bfr[i] = *(const short8*)(lB + ((n * 64 + kOff) ^ ((n & 7) << 3)));
      }
#pragma unroll
      for (int mi = 0; mi < 4; ++mi)
#pragma unroll
        for (int ni = 0; ni < 4; ++ni)
          acc[mi][ni] = __builtin_amdgcn_mfma_f32_16x16x32_bf16(af[mi], bfr[ni], acc[mi][ni], 0, 0, 0);
    }
  }
  if (n0 < ASTR) {
#pragma unroll
    for (int mi = 0; mi < 4; ++mi) {
      const int row = m0 + wm * 64 + mi * 16 + ((lane >> 4) << 2);
#pragma unroll
      for (int ni = 0; ni < 4; ++ni) {
        const int col = n0 + wn * 64 + ni * 16 + (lane & 15);
#pragma unroll
        for (int r = 0; r < 4; ++r)
          C[(size_t)(row + r) * ASTR + col] = f2bf(acc[mi][ni][r]);
      }
    }
  } else {
#pragma unroll
    for (int mi = 0; mi < 4; ++mi) {
      const int row = m0 + wm * 64 + mi * 16 + ((lane >> 4) << 2);
      const int b_ = row >> 11, s_ = row & 2047;
#pragma unroll
      for (int ni = 0; ni < 4; ++ni) {
        const int colv = (n0 - ASTR) + wn * 64 + ni * 16 + (lane & 15);
        u16x4 pk;
#pragma unroll
        for (int r = 0; r < 4; ++r) pk[r] = f2bf(acc[mi][ni][r]);
        *(u16x4*)(Vt + ((size_t)(b_ * NKVH + (colv >> 7)) * HDIM + (colv & 127)) * SLEN + s_) = pk;
      }
    }
  }
}

// ============ 256x256 8-phase GEMM body (r4-proven, for o-proj) ============
#define KD 4096
#define NT 64

#define STAGE_A_(nb, kt, mh)                                                   \
  { _Pragma("unroll") for (int r_ = 0; r_ < 2; ++r_) {                         \
      const int base_ = (mh)*64 + r_*128 + wave*8;                             \
      const int lr_ = base_ + (lane>>3);                                       \
      gload_lds16(Ag + (size_t)(m0 + lr_)*KD + (kt)*64 + (((lane&7) ^ (lr_&7))<<3), \
                  lA[nb] + base_*64); } }

#define STAGE_B_(nb, kt, nh)                                                   \
  { _Pragma("unroll") for (int r_ = 0; r_ < 2; ++r_) {                         \
      const int w8_ = r_*64 + wave*8;                                          \
      const int base_ = ((w8_>>5)<<6) + (nh)*32 + (w8_&31);                    \
      const int nr_ = base_ + (lane>>3);                                       \
      gload_lds16(Bg + (size_t)(n0 + nr_)*KD + (kt)*64 + (((lane&7) ^ (nr_&7))<<3), \
                  lB[nb] + base_*64); } }

#define DS_PHASE(buf, mh, nh)                                                  \
  { const int kb_ = lane >> 4;                                                 \
    _Pragma("unroll") for (int ks = 0; ks < 2; ++ks) {                         \
      _Pragma("unroll") for (int i = 0; i < 4; ++i) {                          \
        const int lr_ = wm*128 + (mh)*64 + i*16 + (lane & 15);                 \
        af[i][ks] = *(const short8*)(lA[buf] + lr_*64 + (((ks*4+kb_) ^ (lr_&7))<<3)); } \
      _Pragma("unroll") for (int j = 0; j < 2; ++j) {                          \
        const int nr_ = wn*64 + (nh)*32 + j*16 + (lane & 15);                  \
        bf[j][ks] = *(const short8*)(lB[buf] + nr_*64 + (((ks*4+kb_) ^ (nr_&7))<<3)); } } }

#define MFMA_PHASE(mh, nh)                                                     \
  __builtin_amdgcn_s_setprio(1);                                               \
  _Pragma("unroll") for (int ks = 0; ks < 2; ++ks)                             \
    _Pragma("unroll") for (int i = 0; i < 4; ++i)                              \
      _Pragma("unroll") for (int j = 0; j < 2; ++j)                            \
        acc[(mh)*4+i][(nh)*2+j] = __builtin_amdgcn_mfma_f32_16x16x32_bf16(     \
            af[i][ks], bf[j][ks], acc[(mh)*4+i][(nh)*2+j], 0, 0, 0);           \
  __builtin_amdgcn_s_setprio(0);

#define BAR()  __builtin_amdgcn_s_barrier(); asm volatile("" ::: "memory")
#define VMW(n) asm volatile("s_waitcnt vmcnt(" #n ")" ::: "memory")

#define GEMM8P_BODY                                                            \
  __shared__ __align__(16) u16 lA[2][256*64];                                  \
  __shared__ __align__(16) u16 lB[2][256*64];                                  \
  const int tid = threadIdx.x, lane = tid & 63, wave = tid >> 6;               \
  const int wm = wave >> 2, wn = wave & 3;                                     \
  f32x4 acc[8][4];                                                             \
  _Pragma("unroll") for (int mi = 0; mi < 8; ++mi)                             \
    _Pragma("unroll") for (int ni = 0; ni < 4; ++ni)                           \
      acc[mi][ni] = (f32x4){0.f, 0.f, 0.f, 0.f};                               \
  short8 af[4][2], bf[2][2];                                                   \
  STAGE_A_(0, 0, 0); STAGE_B_(0, 0, 0); STAGE_A_(0, 0, 1); STAGE_B_(0, 0, 1);  \
  VMW(4); BAR();                                                               \
  for (int t = 0; t < NT - 1; ++t) {                                           \
    const int cur = t & 1, nxt = cur ^ 1;                                      \
    DS_PHASE(cur, 0, 0);                                                       \
    STAGE_A_(nxt, t + 1, 0);                                                   \
    BAR();                                                                     \
    MFMA_PHASE(0, 0);                                                          \
    VMW(2); BAR();                                                             \
    DS_PHASE(cur, 0, 1);                                                       \
    STAGE_B_(nxt, t + 1, 0);                                                   \
    BAR();                                                                     \
    MFMA_PHASE(0, 1);                                                          \
    BAR();                                                                     \
    DS_PHASE(cur, 1, 0);                                                       \
    STAGE_A_(nxt, t + 1, 1);                                                   \
    BAR();                                                                     \
    MFMA_PHASE(1, 0);                                                          \
    BAR();                                                                     \
    DS_PHASE(cur, 1, 1);                                                       \
    STAGE_B_(nxt, t + 1, 1);                                                   \
    BAR();                                                                     \
    MFMA_PHASE(1, 1);                                                          \
    VMW(4); BAR();                                                             \
  }                                                                            \
  {                                                                            \
    const int cur = (NT - 1) & 1;                                              \
    DS_PHASE(cur, 0, 0);                                                       \
    BAR();                                                                     \
    MFMA_PHASE(0, 0);                                                          \
    VMW(0); BAR();                                                             \
    DS_PHASE(cur, 0, 1);                                                       \
    BAR();                                                                     \
    MFMA_PHASE(0, 1);                                                          \
    BAR();                                                                     \
    DS_PHASE(cur, 1, 0);                                                       \
    BAR();                                                                     \
    MFMA_PHASE(1, 0);                                                          \
    BAR();                                                                     \
    DS_PHASE(cur, 1, 1);                                                       \
    BAR();                                                                     \
    MFMA_PHASE(1, 1);                                                          \
  }

__global__ __launch_bounds__(512, 2) void k_gemm_o_8p(
    const u16* __restrict__ Ag, const u16* __restrict__ Bg,
    const float* __restrict__ resid, float* __restrict__ out) {
  // 256 blocks, XCD-chunked bijective remap
  const int wg = (blockIdx.x & 7) * 32 + (blockIdx.x >> 3);
  const int m0 = (wg & 15) * 256;
  const int n0 = (wg >> 4) * 256;
  GEMM8P_BODY
#pragma unroll
  for (int mi = 0; mi < 8; ++mi) {
    const int row = m0 + wm * 128 + mi * 16 + ((lane >> 4) << 2);
#pragma unroll
    for (int ni = 0; ni < 4; ++ni) {
      const int col = n0 + wn * 64 + ni * 16 + (lane & 15);
#pragma unroll
      for (int r = 0; r < 4; ++r) {
        const size_t idx = (size_t)(row + r) * HID + col;
        out[idx] = acc[mi][ni][r] + resid[idx];
      }
    }
  }
}

// ---------------- fused-dequant GEMMs (fallback when ws is small) ----------------
__global__ __launch_bounds__(256) void k_gemm_qkv(
    const u16* __restrict__ A,
    const int* __restrict__ Wq, const int* __restrict__ Wk, const int* __restrict__ Wv,
    const float* __restrict__ Sq, const float* __restrict__ Sk, const float* __restrict__ Sv,
    u16* __restrict__ C, u16* __restrict__ Vt) {
  __shared__ __align__(16) u16 lA[BM * BK];
  __shared__ __align__(16) u16 lB[BN * BK];
  const int tid = threadIdx.x;
  const int lane = tid & 63;
  const int wave = tid >> 6;
  const int wm = wave >> 1, wn = wave & 1;
  const int m0 = blockIdx.x * BM;
  const int n0 = blockIdx.y * BN;

  const int* W; const float* Ws; int nb;
  if (n0 < NQK)       { W = Wq; Ws = Sq; nb = n0; }
  else if (n0 < ASTR) { W = Wk; Ws = Sk; nb = n0 - NQK; }
  else                { W = Wv; Ws = Sv; nb = n0 - ASTR; }

  const int mloc = wave * 8 + (lane >> 3);
  const int lb8 = (((lane & 7) ^ (lane >> 3)) << 3);

  f32x4 acc[4][4];
#pragma unroll
  for (int mi = 0; mi < 4; ++mi)
#pragma unroll
    for (int ni = 0; ni < 4; ++ni) acc[mi][ni] = (f32x4){0.f, 0.f, 0.f, 0.f};

  for (int k0 = 0; k0 < HID; k0 += BK) {
    __syncthreads();
#pragma unroll
    for (int p = 0; p < 4; ++p)
      gload_lds16(A + (size_t)(m0 + p * 32 + mloc) * HID + k0 + lb8,
                  lA + p * 2048 + wave * 512);
    const int grp = k0 >> 7;
#pragma unroll
    for (int p = 0; p < 8; ++p) {
      const int n = p * 16 + (tid >> 4);
      const int kk = (tid & 15) * 4;
      int4v wv4 = *(const int4v*)(W + (size_t)(nb + n) * HID + k0 + kk);
      const float sc = Ws[(nb + n) * 32 + grp];
      unsigned lo = (unsigned)f2bf((float)(wv4[0] - 8) * sc) |
                    ((unsigned)f2bf((float)(wv4[1] - 8) * sc) << 16);
      unsigned hi = (unsigned)f2bf((float)(wv4[2] - 8) * sc) |
                    ((unsigned)f2bf((float)(wv4[3] - 8) * sc) << 16);
      const int di = (n * 64 + kk) ^ ((n & 7) << 3);
      unsigned* dst = (unsigned*)(lB + di);
      dst[0] = lo; dst[1] = hi;
    }
    __syncthreads();
#pragma unroll
    for (int kc = 0; kc < 2; ++kc) {
      const int kOff = kc * 32 + ((lane >> 4) << 3);
      short8 af[4], bfr[4];
#pragma unroll
      for (int i = 0; i < 4; ++i) {
        const int m = wm * 64 + i * 16 + (lane & 15);
        af[i] = *(const short8*)(lA + ((m * 64 + kOff) ^ ((m & 7) << 3)));
        const int n = wn * 64 + i * 16 + (lane & 15);
        bfr[i] = *(const short8*)(lB + ((n * 64 + kOff) ^ ((n & 7) << 3)));
      }
#pragma unroll
      for (int mi = 0; mi < 4; ++mi)
#pragma unroll
        for (int ni = 0; ni < 4; ++ni)
          acc[mi][ni] = __builtin_amdgcn_mfma_f32_16x16x32_bf16(af[mi], bfr[ni], acc[mi][ni], 0, 0, 0);
    }
  }
  if (n0 < ASTR) {
#pragma unroll
    for (int mi = 0; mi < 4; ++mi) {
      const int row = m0 + wm * 64 + mi * 16 + ((lane >> 4) << 2);
#pragma unroll
      for (int ni = 0; ni < 4; ++ni) {
        const int col = n0 + wn * 64 + ni * 16 + (lane & 15);
#pragma unroll
        for (int r = 0; r < 4; ++r)
          C[(size_t)(row + r) * ASTR + col] = f2bf(acc[mi][ni][r]);
      }
    }
  } else {
#pragma unroll
    for (int mi = 0; mi < 4; ++mi) {
      const int row = m0 + wm * 64 + mi * 16 + ((lane >> 4) << 2);
      const int b_ = row >> 11, s_ = row & 2047;
#pragma unroll
      for (int ni = 0; ni < 4; ++ni) {
        const int colv = (n0 - ASTR) + wn * 64 + ni * 16 + (lane & 15);
        u16x4 pk;
#pragma unroll
        for (int r = 0; r < 4; ++r) pk[r] = f2bf(acc[mi][ni][r]);
        *(u16x4*)(Vt + ((size_t)(b_ * NKVH + (colv >> 7)) * HDIM + (colv & 127)) * SLEN + s_) = pk;
      }
    }
  }
}

__global__ __launch_bounds__(256) void k_gemm_o(
    const u16* __restrict__ A, const int* __restrict__ W, const float* __restrict__ Ws,
    const float* __restrict__ resid, float* __restrict__ out) {
  __shared__ __align__(16) u16 lA[BM * BK];
  __shared__ __align__(16) u16 lB[BN * BK];
  const int tid = threadIdx.x;
  const int lane = tid & 63;
  const int wave = tid >> 6;
  const int wm = wave >> 1, wn = wave & 1;
  const int m0 = blockIdx.x * BM;
  const int n0 = blockIdx.y * BN;

  const int mloc = wave * 8 + (lane >> 3);
  const int lb8 = (((lane & 7) ^ (lane >> 3)) << 3);

  f32x4 acc[4][4];
#pragma unroll
  for (int mi = 0; mi < 4; ++mi)
#pragma unroll
    for (int ni = 0; ni < 4; ++ni) acc[mi][ni] = (f32x4){0.f, 0.f, 0.f, 0.f};

  for (int k0 = 0; k0 < NQK; k0 += BK) {
    __syncthreads();
#pragma unroll
    for (int p = 0; p < 4; ++p)
      gload_lds16(A + (size_t)(m0 + p * 32 + mloc) * NQK + k0 + lb8,
                  lA + p * 2048 + wave * 512);
    const int grp = k0 >> 7;
#pragma unroll
    for (int p = 0; p < 8; ++p) {
      const int n = p * 16 + (tid >> 4);
      const int kk = (tid & 15) * 4;
      int4v wv4 = *(const int4v*)(W + (size_t)(n0 + n) * NQK + k0 + kk);
      const float sc = Ws[(n0 + n) * 32 + grp];
      unsigned lo = (unsigned)f2bf((float)(wv4[0] - 8) * sc) |
                    ((unsigned)f2bf((float)(wv4[1] - 8) * sc) << 16);
      unsigned hi = (unsigned)f2bf((float)(wv4[2] - 8) * sc) |
                    ((unsigned)f2bf((float)(wv4[3] - 8) * sc) << 16);
      const int di = (n * 64 + kk) ^ ((n & 7) << 3);
      unsigned* dst = (unsigned*)(lB + di);
      dst[0] = lo; dst[1] = hi;
    }
    __syncthreads();
#pragma unroll
    for (int kc = 0; kc < 2; ++kc) {
      const int kOff = kc * 32 + ((lane >> 4) << 3);
      short8 af[4], bfr[4];
#pragma unroll
      for (int i = 0; i < 4; ++i) {
        const int m = wm * 64 + i * 16 + (lane & 15);
        af[i] = *(const short8*)(lA + ((m * 64 + kOff) ^ ((m & 7) << 3)));
        const int n = wn * 64 + i * 16 + (lane & 15);
        bfr[i] = *(const short8*)(lB + ((n * 64 + kOff) ^ ((n & 7) << 3)));
      }
#pragma unroll
      for (int mi = 0; mi < 4; ++mi)
#pragma unroll
        for (int ni = 0; ni < 4; ++ni)
          acc[mi][ni] = __builtin_amdgcn_mfma_f32_16x16x32_bf16(af[mi], bfr[ni], acc[mi][ni], 0, 0, 0);
      }
  }
#pragma unroll
  for (int mi = 0; mi < 4; ++mi) {
    const int row = m0 + wm * 64 + mi * 16 + ((lane >> 4) << 2);
#pragma unroll
    for (int ni = 0; ni < 4; ++ni) {
      const int col = n0 + wn * 64 + ni * 16 + (lane & 15);
#pragma unroll
      for (int r = 0; r < 4; ++r) {
        const size_t idx = (size_t)(row + r) * HID + col;
        out[idx] = acc[mi][ni][r] + resid[idx];
      }
    }
  }
}

// ------ RoPE in-place on q,k — vectorized short8 (8 d-pairs per thread) ------
__global__ __launch_bounds__(256) void k_rope(u16* __restrict__ qk,
                                              const float* __restrict__ cosb,
                                              const float* __restrict__ sinb) {
  const int idx = blockIdx.x * 256 + threadIdx.x;   // NTOK*40*8 total
  const int d8 = (idx & 7) * 8;                      // 0..56
  const int hh = (idx >> 3) % 40;
  const int t = idx / 320;
  const int col = (hh < 32) ? hh * HDIM : NQK + (hh - 32) * HDIM;
  u16* p = qk + (size_t)t * ASTR + col;
  const float* cb = cosb + (size_t)t * HDIM + d8;
  const float* sb = sinb + (size_t)t * HDIM + d8;
  float4 c0 = *(const float4*)cb, c1 = *(const float4*)(cb + 4);
  float4 s0 = *(const float4*)sb, s1 = *(const float4*)(sb + 4);
  const float cv[8] = {c0.x, c0.y, c0.z, c0.w, c1.x, c1.y, c1.z, c1.w};
  const float sv[8] = {s0.x, s0.y, s0.z, s0.w, s1.x, s1.y, s1.z, s1.w};
  short8 x1v = *(const short8*)(p + d8);
  short8 x2v = *(const short8*)(p + d8 + 64);
  u16 o1[8], o2[8];
#pragma unroll
  for (int j = 0; j < 8; ++j) {
    const float x1 = bf2f((u16)x1v[j]), x2 = bf2f((u16)x2v[j]);
    o1[j] = f2bf(x1 * cv[j] - x2 * sv[j]);
    o2[j] = f2bf(x2 * cv[j] + x1 * sv[j]);
  }
  *(short8*)(p + d8)      = *(short8*)o1;
  *(short8*)(p + d8 + 64) = *(short8*)o2;
}

// ---------------- flash attention (GQA, causal) — r9-proven (banked) ----------------
__global__ __launch_bounds__(256) void k_attn(const u16* __restrict__ qk,
                                              const u16* __restrict__ vt,
                                              u16* __restrict__ o) {
  const int slot = blockIdx.x;
  const int w = (slot & 7) * 128 + (slot >> 3);
  const int qi = 15 - (w & 15);
  const int h = (w >> 4) & 31;
  const int b = w >> 9;
  const int kvh = h >> 2;
  const int q0 = qi * 128;
  const int lane = threadIdx.x & 63, wave = threadIdx.x >> 6;
  const int m = lane & 15, kg = lane >> 4;

  const u16* Qb = qk + (size_t)b * SLEN * ASTR + h * HDIM;
  const u16* Kb = qk + (size_t)b * SLEN * ASTR + NQK + kvh * HDIM;
  const u16* Vb = vt + (size_t)(b * NKVH + kvh) * HDIM * SLEN;

  __shared__ __align__(16) u16 Kt[64 * 128];
  __shared__ __align__(16) u16 Vts[128 * 64];
  __shared__ __align__(16) u16 Pl[4][32 * 72];

  const int qr = q0 + wave * 32;
  short8 qf[2][4];
#pragma unroll
  for (int mi = 0; mi < 2; ++mi)
#pragma unroll
    for (int kc = 0; kc < 4; ++kc)
      qf[mi][kc] = *(const short8*)(Qb + (size_t)(qr + mi * 16 + m) * ASTR + kc * 32 + kg * 8);

  f32x4 oacc[2][8];
#pragma unroll
  for (int mi = 0; mi < 2; ++mi)
#pragma unroll
    for (int n = 0; n < 8; ++n) oacc[mi][n] = (f32x4){0.f, 0.f, 0.f, 0.f};
  float rm[2][4], rl[2][4];
#pragma unroll
  for (int mi = 0; mi < 2; ++mi)
#pragma unroll
    for (int r = 0; r < 4; ++r) { rm[mi][r] = -3.0e38f; rl[mi][r] = 0.f; }

  const float sscale = 0.08838834764831845f;
  const int nt = q0 / 64 + 2;
  for (int t = 0; t < nt; ++t) {
    const int kv0 = t * 64;
    __syncthreads();
#pragma unroll
    for (int p = 0; p < 4; ++p) {
      const int row = p * 16 + wave * 4 + (lane >> 4);
      const int c8s = (lane & 15) ^ (row & 7);
      gload_lds16(Kb + (size_t)(kv0 + row) * ASTR + c8s * 8, Kt + p * 2048 + wave * 512);
    }
#pragma unroll
    for (int p = 0; p < 4; ++p) {
      const int d = p * 32 + wave * 8 + (lane >> 3);
      const int c8s = (lane & 7) ^ (d & 7);
      gload_lds16(Vb + (size_t)d * SLEN + kv0 + c8s * 8, Vts + p * 2048 + wave * 512);
    }
    __syncthreads();

    f32x4 sf[2][4];
#pragma unroll
    for (int mi = 0; mi < 2; ++mi)
#pragma unroll
      for (int ni = 0; ni < 4; ++ni) sf[mi][ni] = (f32x4){0.f, 0.f, 0.f, 0.f};
    __builtin_amdgcn_s_setprio(1);
#pragma unroll
    for (int ni = 0; ni < 4; ++ni)
#pragma unroll
      for (int kc = 0; kc < 4; ++kc) {
        const int krow = ni * 16 + m;
        short8 kf = *(const short8*)(Kt + krow * 128 + (((kc * 4 + kg) ^ (krow & 7)) << 3));
#pragma unroll
        for (int mi = 0; mi < 2; ++mi)
          sf[mi][ni] = __builtin_amdgcn_mfma_f32_16x16x32_bf16(qf[mi][kc], kf, sf[mi][ni], 0, 0, 0);
      }
    __builtin_amdgcn_s_setprio(0);

#pragma unroll
    for (int mi = 0; mi < 2; ++mi) {
      const bool dg = (kv0 + 63 > qr + mi * 16);
      float tmax[4] = {-3.0e38f, -3.0e38f, -3.0e38f, -3.0e38f};
#pragma unroll
      for (int ni = 0; ni < 4; ++ni)
#pragma unroll
        for (int r = 0; r < 4; ++r) {
          float s = sf[mi][ni][r] * sscale;
          if (dg) {
            const int rowg = qr + mi * 16 + kg * 4 + r;
            const int colg = kv0 + ni * 16 + m;
            if (colg > rowg) s = -1e30f;
          }
          sf[mi][ni][r] = s;
          tmax[r] = fmaxf(tmax[r], s);
        }
#pragma unroll
      for (int r = 0; r < 4; ++r)
#pragma unroll
        for (int off = 1; off < 16; off <<= 1)
          tmax[r] = fmaxf(tmax[r], __shfl_xor(tmax[r], off));
      float scl[4], psum[4];
#pragma unroll
      for (int r = 0; r < 4; ++r) {
        const float mn = fmaxf(rm[mi][r], tmax[r]);
        scl[r] = __expf(rm[mi][r] - mn);
        rm[mi][r] = mn;
        psum[r] = 0.f;
      }
#pragma unroll
      for (int ni = 0; ni < 4; ++ni)
#pragma unroll
        for (int r = 0; r < 4; ++r) {
          const float p = __expf(sf[mi][ni][r] - rm[mi][r]);
          psum[r] += p;
          Pl[wave][(mi * 16 + kg * 4 + r) * 72 + ni * 16 + m] = f2bf(p);
        }
#pragma unroll
      for (int r = 0; r < 4; ++r) {
#pragma unroll
        for (int off = 1; off < 16; off <<= 1)
          psum[r] += __shfl_xor(psum[r], off);
        rl[mi][r] = rl[mi][r] * scl[r] + psum[r];
      }
#pragma unroll
      for (int n = 0; n < 8; ++n)
#pragma unroll
        for (int r = 0; r < 4; ++r) oacc[mi][n][r] *= scl[r];
    }

    __builtin_amdgcn_s_setprio(1);
#pragma unroll
    for (int kc = 0; kc < 2; ++kc) {
      short8 pf[2];
#pragma unroll
      for (int mi = 0; mi < 2; ++mi)
        pf[mi] = *(const short8*)(&Pl[wave][(mi * 16 + m) * 72 + kc * 32 + kg * 8]);
#pragma unroll
      for (int n = 0; n < 8; ++n) {
        const int vrow = n * 16 + m;
        short8 vf = *(const short8*)(Vts + vrow * 64 + (((kc * 4 + kg) ^ (vrow & 7)) << 3));
#pragma unroll
        for (int mi = 0; mi < 2; ++mi)
          oacc[mi][n] = __builtin_amdgcn_mfma_f32_16x16x32_bf16(pf[mi], vf, oacc[mi][n], 0, 0, 0);
      }
    }
    __builtin_amdgcn_s_setprio(0);
  }

#pragma unroll
  for (int mi = 0; mi < 2; ++mi) {
    float inv[4];
#pragma unroll
    for (int r = 0; r < 4; ++r) inv[r] = 1.0f / rl[mi][r];
#pragma unroll
    for (int n = 0; n < 8; ++n)
#pragma unroll
      for (int r = 0; r < 4; ++r) {
        const int row = qr + mi * 16 + kg * 4 + r;
        o[((size_t)b * SLEN + row) * NQK + h * HDIM + n * 16 + m] = f2bf(oacc[mi][n][r] * inv[r]);
      }
  }
}

extern "C" void kernel_launch(void* const* d_in, const int* in_sizes, int n_in,
                              void* d_out, int out_size, void* d_ws, size_t ws_size,
                              hipStream_t stream) {
  (void)in_sizes; (void)n_in; (void)out_size;
  const float* x    = (const float*)d_in[0];
  const float* lnw  = (const float*)d_in[1];
  const float* cosb = (const float*)d_in[2];
  const float* sinb = (const float*)d_in[3];
  const float* sq   = (const float*)d_in[4];
  const float* sk   = (const float*)d_in[5];
  const float* sv   = (const float*)d_in[6];
  const float* so   = (const float*)d_in[7];
  const int* wq     = (const int*)d_in[8];
  const int* wk     = (const int*)d_in[9];
  const int* wv     = (const int*)d_in[10];
  const int* wo     = (const int*)d_in[11];

  u16* h   = (u16*)d_ws;                       // [NTOK][HID]; reused as attn output
  u16* qkb = h + (size_t)NTOK * HID;           // [NTOK][ASTR] (q,k)
  u16* vtb = qkb + (size_t)NTOK * ASTR;        // [B][NKVH][HDIM][SLEN]
  u16* wqkvb = vtb + (size_t)BATCH * NKVH * HDIM * SLEN;  // [NQKV][HID] bf16
  u16* wob   = wqkvb + (size_t)NQKV * HID;                // [HID][NQK] bf16
  float* out = (float*)d_out;

  const size_t need = ((size_t)NTOK * HID + (size_t)NTOK * ASTR +
                       (size_t)BATCH * NKVH * HDIM * SLEN +
                       (size_t)NQKV * HID + (size_t)HID * NQK) * sizeof(u16);
  const bool predeq = (ws_size >= need);

  k_rmsnorm<<<NTOK, 256, 0, stream>>>(x, lnw, h);

  if (predeq) {
    k_deq_all<<<(10240 * 512) / 256, 256, 0, stream>>>(wq, wk, wv, wo, sq, sk, sv, so, wqkvb);
    dim3 g1(NTOK / BM, NQKV / BN);
    k_gemm_qkv_b<<<g1, 256, 0, stream>>>(h, wqkvb, qkb, vtb);
  } else {
    dim3 g1(NTOK / BM, NQKV / BN);
    k_gemm_qkv<<<g1, 256, 0, stream>>>(h, wq, wk, wv, sq, sk, sv, qkb, vtb);
  }

  k_rope<<<(NTOK * 40 * 8) / 256, 256, 0, stream>>>(qkb, cosb, sinb);

  k_attn<<<1024, 256, 0, stream>>>(qkb, vtb, h);

  if (predeq) {
    k_gemm_o_8p<<<256, 512, 0, stream>>>(h, wob, x, out);
  } else {
    dim3 g3(NTOK / BM, HID / BN);
    k_gemm_o<<<g3, 256, 0, stream>>>(h, wo, so, x, out);
  }
}